// Round 1
// baseline (5650.145 us; speedup 1.0000x reference)
//
#include <hip/hip_runtime.h>
#include <math.h>

#define NFEAT 256
#define HID 64
#define NCLS 6

// ---------------- degree / normalization ----------------

__global__ __launch_bounds__(256) void k_init_cnt(int* __restrict__ cnt, int n) {
  int i = blockIdx.x * 256 + threadIdx.x;
  if (i < n) cnt[i] = 1;  // self-loop
}

__global__ __launch_bounds__(256) void k_count(const int* __restrict__ dst,
                                               int* __restrict__ cnt, int E) {
  int i = blockIdx.x * 256 + threadIdx.x;
  if (i < E) atomicAdd(&cnt[dst[i]], 1);
}

__global__ __launch_bounds__(256) void k_dis(const int* __restrict__ cnt,
                                             float* __restrict__ dis, int n) {
  int i = blockIdx.x * 256 + threadIdx.x;
  if (i < n) dis[i] = 1.0f / sqrtf((float)cnt[i]);
}

// ---------------- GEMM: G[row] = dis[row] * (X[row,:] @ W), W is K x 64 ----------------
// block = 256 threads, tile = 64 rows x 64 cols, thread = 4 rows x 4 cols, K chunked by 64.

template<int K>
__global__ __launch_bounds__(256) void k_gemm_scaled(const float* __restrict__ X,
                                                     const float* __restrict__ W,
                                                     const float* __restrict__ dis,
                                                     float* __restrict__ G, int n) {
  __shared__ float Wl[64 * 64];
  __shared__ float Xl[64 * 64];
  const int tid = threadIdx.x;
  const int row0 = blockIdx.x * 64;
  const int tc = tid & 15;   // cols tc*4 .. tc*4+3
  const int tr = tid >> 4;   // rows tr*4 .. tr*4+3
  float acc[4][4] = {};

  for (int k0 = 0; k0 < K; k0 += 64) {
    __syncthreads();
#pragma unroll
    for (int i = 0; i < 4; ++i) {  // stage W chunk [64][64]
      int idx = tid * 4 + i * 1024;
      int kr = idx >> 6, c = idx & 63;
      *(float4*)&Wl[idx] = *(const float4*)&W[(size_t)(k0 + kr) * 64 + c];
    }
#pragma unroll
    for (int i = 0; i < 4; ++i) {  // stage X chunk [64 rows][64 k]
      int idx = tid * 4 + i * 1024;
      int r = idx >> 6, c = idx & 63;
      int row = row0 + r;
      float4 v = make_float4(0.f, 0.f, 0.f, 0.f);
      if (row < n) v = *(const float4*)&X[(size_t)row * K + k0 + c];
      *(float4*)&Xl[idx] = v;
    }
    __syncthreads();
#pragma unroll 4
    for (int kk = 0; kk < 64; kk += 4) {
      float4 xv[4], wv[4];
#pragma unroll
      for (int r = 0; r < 4; ++r) xv[r] = *(float4*)&Xl[(tr * 4 + r) * 64 + kk];
#pragma unroll
      for (int q = 0; q < 4; ++q) wv[q] = *(float4*)&Wl[(kk + q) * 64 + tc * 4];
#pragma unroll
      for (int r = 0; r < 4; ++r) {
        const float xr[4] = {xv[r].x, xv[r].y, xv[r].z, xv[r].w};
#pragma unroll
        for (int q = 0; q < 4; ++q) {
          acc[r][0] += xr[q] * wv[q].x;
          acc[r][1] += xr[q] * wv[q].y;
          acc[r][2] += xr[q] * wv[q].z;
          acc[r][3] += xr[q] * wv[q].w;
        }
      }
    }
  }
#pragma unroll
  for (int r = 0; r < 4; ++r) {
    int row = row0 + tr * 4 + r;
    if (row < n) {
      float s = dis[row];
      float4 o = make_float4(acc[r][0] * s, acc[r][1] * s, acc[r][2] * s, acc[r][3] * s);
      *(float4*)&G[(size_t)row * 64 + tc * 4] = o;
    }
  }
}

// ---------------- edge scatter: acc[dst] += g[src] ----------------
// 16 lanes per edge, float4 per lane; wave handles 4 edges.

__global__ __launch_bounds__(256) void k_agg(const int* __restrict__ src,
                                             const int* __restrict__ dst,
                                             const float* __restrict__ g,
                                             float* __restrict__ acc, int E) {
  int e = blockIdx.x * 16 + (threadIdx.x >> 4);
  if (e >= E) return;
  int f4 = threadIdx.x & 15;
  int s = src[e], d = dst[e];
  float4 hv = *(const float4*)&g[(size_t)s * 64 + f4 * 4];
  float* p = &acc[(size_t)d * 64 + f4 * 4];
  atomicAdd(p + 0, hv.x);
  atomicAdd(p + 1, hv.y);
  atomicAdd(p + 2, hv.z);
  atomicAdd(p + 3, hv.w);
}

// ---------------- finalize: a[v] = relu(dis[v]*(acc[v] + g[v]) + b) ----------------
// (self-loop term dis^2*h == dis*g, folded in)

__global__ __launch_bounds__(256) void k_finalize(const float* __restrict__ accb,
                                                  const float* __restrict__ g,
                                                  const float* __restrict__ dis,
                                                  const float* __restrict__ b,
                                                  float* __restrict__ outp, int n) {
  int i = blockIdx.x * 256 + threadIdx.x;  // float4 index over n*16
  if (i >= n * 16) return;
  int row = i >> 4, f4 = i & 15;
  float dv = dis[row];
  float4 a = ((const float4*)accb)[i];
  float4 gg = ((const float4*)g)[i];
  const float* bp = &b[f4 * 4];
  float4 o;
  o.x = fmaxf(fmaf(dv, a.x + gg.x, bp[0]), 0.f);
  o.y = fmaxf(fmaf(dv, a.y + gg.y, bp[1]), 0.f);
  o.z = fmaxf(fmaf(dv, a.z + gg.z, bp[2]), 0.f);
  o.w = fmaxf(fmaf(dv, a.w + gg.w, bp[3]), 0.f);
  ((float4*)outp)[i] = o;
}

// ---------------- final FC: out[row] = A[row,:] @ Wfc + bfc ----------------

__global__ __launch_bounds__(256) void k_fc(const float* __restrict__ A,
                                            const float* __restrict__ Wfc,
                                            const float* __restrict__ bfc,
                                            float* __restrict__ outp, int n) {
  __shared__ float Wl[64 * NCLS];
  __shared__ float bl[8];
  int tid = threadIdx.x;
  for (int i = tid; i < 64 * NCLS; i += 256) Wl[i] = Wfc[i];
  if (tid < NCLS) bl[tid] = bfc[tid];
  __syncthreads();
  int row = blockIdx.x * 256 + tid;
  if (row >= n) return;
  float accv[NCLS];
#pragma unroll
  for (int j = 0; j < NCLS; ++j) accv[j] = bl[j];
  const float4* a4 = (const float4*)&A[(size_t)row * 64];
#pragma unroll
  for (int k4 = 0; k4 < 16; ++k4) {
    float4 a = a4[k4];
    const float av[4] = {a.x, a.y, a.z, a.w};
#pragma unroll
    for (int q = 0; q < 4; ++q)
#pragma unroll
      for (int j = 0; j < NCLS; ++j) accv[j] += av[q] * Wl[(k4 * 4 + q) * NCLS + j];
  }
#pragma unroll
  for (int j = 0; j < NCLS; ++j) outp[(size_t)row * NCLS + j] = accv[j];
}

// ---------------- launch ----------------

extern "C" void kernel_launch(void* const* d_in, const int* in_sizes, int n_in,
                              void* d_out, int out_size, void* d_ws, size_t ws_size,
                              hipStream_t stream) {
  const float* x   = (const float*)d_in[0];
  const int*   ei  = (const int*)d_in[1];
  const float* W1  = (const float*)d_in[2];
  const float* b1  = (const float*)d_in[3];
  const float* W2  = (const float*)d_in[4];
  const float* b2  = (const float*)d_in[5];
  const float* Wfc = (const float*)d_in[6];
  const float* bfc = (const float*)d_in[7];
  float* out = (float*)d_out;

  const int n = in_sizes[0] / NFEAT;   // 100000
  const int E = in_sizes[1] / 2;       // 3200000
  const int* src = ei;
  const int* dst = ei + E;

  char* ws = (char*)d_ws;
  size_t off = 0;
  auto alloc = [&](size_t bytes) -> void* {
    void* p = (void*)(ws + off);
    off += (bytes + 255) & ~(size_t)255;
    return p;
  };
  int*   cnt  = (int*)alloc((size_t)n * 4);
  float* dis  = (float*)alloc((size_t)n * 4);
  float* bufA = (float*)alloc((size_t)n * HID * 4);  // g (scaled GEMM out)
  float* bufB = (float*)alloc((size_t)n * HID * 4);  // acc / layer output

  const size_t nodeBytes = (size_t)n * HID * 4;

  // normalization
  k_init_cnt<<<(n + 255) / 256, 256, 0, stream>>>(cnt, n);
  k_count<<<(E + 255) / 256, 256, 0, stream>>>(dst, cnt, E);
  k_dis<<<(n + 255) / 256, 256, 0, stream>>>(cnt, dis, n);

  // layer 1: g1 = dis * (x @ W1); acc = scatter(g1); a1 = relu(dis*(acc+g1)+b1)
  k_gemm_scaled<NFEAT><<<(n + 63) / 64, 256, 0, stream>>>(x, W1, dis, bufA, n);
  hipMemsetAsync(bufB, 0, nodeBytes, stream);
  k_agg<<<(E + 15) / 16, 256, 0, stream>>>(src, dst, bufA, bufB, E);
  k_finalize<<<(n * 16 + 255) / 256, 256, 0, stream>>>(bufB, bufA, dis, b1, bufB, n);

  // layer 2 (same, K=64)
  k_gemm_scaled<HID><<<(n + 63) / 64, 256, 0, stream>>>(bufB, W2, dis, bufA, n);
  hipMemsetAsync(bufB, 0, nodeBytes, stream);
  k_agg<<<(E + 15) / 16, 256, 0, stream>>>(src, dst, bufA, bufB, E);
  k_finalize<<<(n * 16 + 255) / 256, 256, 0, stream>>>(bufB, bufA, dis, b2, bufB, n);

  // FC head
  k_fc<<<(n + 255) / 256, 256, 0, stream>>>(bufB, Wfc, bfc, out, n);
}

// Round 2
// 646.697 us; speedup vs baseline: 8.7369x; 8.7369x over previous
//
#include <hip/hip_runtime.h>
#include <math.h>

#define NFEAT 256
#define HID 64
#define NCLS 6

// ---------------- degree / normalization ----------------

__global__ __launch_bounds__(256) void k_zero_int(int* __restrict__ p, int n) {
  int i = blockIdx.x * 256 + threadIdx.x;
  if (i < n) p[i] = 0;
}

__global__ __launch_bounds__(256) void k_count(const int* __restrict__ dst,
                                               int* __restrict__ cnt, int E) {
  int i = blockIdx.x * 256 + threadIdx.x;
  if (i < E) atomicAdd(&cnt[dst[i]], 1);
}

// dis = 1/sqrt(indeg + 1)   (self-loop)
__global__ __launch_bounds__(256) void k_dis(const int* __restrict__ cnt,
                                             float* __restrict__ dis, int n) {
  int i = blockIdx.x * 256 + threadIdx.x;
  if (i < n) dis[i] = 1.0f / sqrtf((float)cnt[i] + 1.0f);
}

// ---------------- CSR build: exclusive scan of cnt -> rowptr, then scatter ----------------

__global__ __launch_bounds__(256) void k_scan_block(const int* __restrict__ cnt,
                                                    int* __restrict__ excl,
                                                    int* __restrict__ bsum, int n) {
  __shared__ int sh[256];
  int t = threadIdx.x;
  int base = blockIdx.x * 1024 + t * 4;
  int v[4];
  int s = 0;
#pragma unroll
  for (int i = 0; i < 4; ++i) {
    v[i] = (base + i < n) ? cnt[base + i] : 0;
    s += v[i];
  }
  sh[t] = s;
  __syncthreads();
  for (int off = 1; off < 256; off <<= 1) {
    int x = sh[t];
    int y = (t >= off) ? sh[t - off] : 0;
    __syncthreads();
    sh[t] = x + y;
    __syncthreads();
  }
  if (t == 255) bsum[blockIdx.x] = sh[255];
  int run = sh[t] - s;  // exclusive prefix of this thread within block
#pragma unroll
  for (int i = 0; i < 4; ++i) {
    if (base + i < n) excl[base + i] = run;
    run += v[i];
  }
}

// single block, nb <= 128
__global__ __launch_bounds__(128) void k_scan_sums(const int* __restrict__ bsum,
                                                   int* __restrict__ boff, int nb,
                                                   int* __restrict__ rowptr_n) {
  __shared__ int sh[128];
  int t = threadIdx.x;
  int v = (t < nb) ? bsum[t] : 0;
  sh[t] = v;
  __syncthreads();
  for (int off = 1; off < 128; off <<= 1) {
    int x = sh[t];
    int y = (t >= off) ? sh[t - off] : 0;
    __syncthreads();
    sh[t] = x + y;
    __syncthreads();
  }
  if (t < nb) boff[t] = sh[t] - v;
  if (t == 127) *rowptr_n = sh[127];  // total == E
}

__global__ __launch_bounds__(256) void k_scan_add(int* __restrict__ excl,
                                                  const int* __restrict__ boff, int n) {
  int off = boff[blockIdx.x];
  int base = blockIdx.x * 1024 + threadIdx.x * 4;
#pragma unroll
  for (int i = 0; i < 4; ++i)
    if (base + i < n) excl[base + i] += off;
}

// group edge sources by destination: srcs[rowptr[d] ...] = all src with dst==d
__global__ __launch_bounds__(256) void k_scatter(const int* __restrict__ src,
                                                 const int* __restrict__ dst,
                                                 const int* __restrict__ rowptr,
                                                 int* __restrict__ cur,
                                                 int* __restrict__ srcs, int E) {
  int i = blockIdx.x * 256 + threadIdx.x;
  if (i >= E) return;
  int d = dst[i];
  int pos = rowptr[d] + atomicAdd(&cur[d], 1);
  srcs[pos] = src[i];
}

// ---------------- GEMM: G[row] = dis[row] * (X[row,:] @ W), W is K x 64 ----------------

template<int K>
__global__ __launch_bounds__(256) void k_gemm_scaled(const float* __restrict__ X,
                                                     const float* __restrict__ W,
                                                     const float* __restrict__ dis,
                                                     float* __restrict__ G, int n) {
  __shared__ float Wl[64 * 64];
  __shared__ float Xl[64 * 64];
  const int tid = threadIdx.x;
  const int row0 = blockIdx.x * 64;
  const int tc = tid & 15;
  const int tr = tid >> 4;
  float acc[4][4] = {};

  for (int k0 = 0; k0 < K; k0 += 64) {
    __syncthreads();
#pragma unroll
    for (int i = 0; i < 4; ++i) {
      int idx = tid * 4 + i * 1024;
      int kr = idx >> 6, c = idx & 63;
      *(float4*)&Wl[idx] = *(const float4*)&W[(size_t)(k0 + kr) * 64 + c];
    }
#pragma unroll
    for (int i = 0; i < 4; ++i) {
      int idx = tid * 4 + i * 1024;
      int r = idx >> 6, c = idx & 63;
      int row = row0 + r;
      float4 v = make_float4(0.f, 0.f, 0.f, 0.f);
      if (row < n) v = *(const float4*)&X[(size_t)row * K + k0 + c];
      *(float4*)&Xl[idx] = v;
    }
    __syncthreads();
#pragma unroll 4
    for (int kk = 0; kk < 64; kk += 4) {
      float4 xv[4], wv[4];
#pragma unroll
      for (int r = 0; r < 4; ++r) xv[r] = *(float4*)&Xl[(tr * 4 + r) * 64 + kk];
#pragma unroll
      for (int q = 0; q < 4; ++q) wv[q] = *(float4*)&Wl[(kk + q) * 64 + tc * 4];
#pragma unroll
      for (int r = 0; r < 4; ++r) {
        const float xr[4] = {xv[r].x, xv[r].y, xv[r].z, xv[r].w};
#pragma unroll
        for (int q = 0; q < 4; ++q) {
          acc[r][0] += xr[q] * wv[q].x;
          acc[r][1] += xr[q] * wv[q].y;
          acc[r][2] += xr[q] * wv[q].z;
          acc[r][3] += xr[q] * wv[q].w;
        }
      }
    }
  }
#pragma unroll
  for (int r = 0; r < 4; ++r) {
    int row = row0 + tr * 4 + r;
    if (row < n) {
      float s = dis[row];
      float4 o = make_float4(acc[r][0] * s, acc[r][1] * s, acc[r][2] * s, acc[r][3] * s);
      *(float4*)&G[(size_t)row * 64 + tc * 4] = o;
    }
  }
}

// ---------------- CSR gather-sum + fused finalize ----------------
// out[v] = relu(dis[v] * (sum_{s in N(v)} g[s] + g[v]) + b)
// 16 lanes per node (float4 each = 64 feats), 16 nodes per block.

__global__ __launch_bounds__(256) void k_agg_csr(const int* __restrict__ rowptr,
                                                 const int* __restrict__ srcs,
                                                 const float* __restrict__ g,
                                                 const float* __restrict__ dis,
                                                 const float* __restrict__ bias,
                                                 float* __restrict__ outp, int n) {
  int v = blockIdx.x * 16 + (threadIdx.x >> 4);
  if (v >= n) return;
  int lane = threadIdx.x & 15;
  int beg = rowptr[v], end = rowptr[v + 1];
  const float4* g4 = (const float4*)g;
  float4 self = g4[(size_t)v * 16 + lane];
  float ax = self.x, ay = self.y, az = self.z, aw = self.w;

  int j = beg;
  for (; j + 4 <= end; j += 4) {
    int s0 = srcs[j], s1 = srcs[j + 1], s2 = srcs[j + 2], s3 = srcs[j + 3];
    float4 a0 = g4[(size_t)s0 * 16 + lane];
    float4 a1 = g4[(size_t)s1 * 16 + lane];
    float4 a2 = g4[(size_t)s2 * 16 + lane];
    float4 a3 = g4[(size_t)s3 * 16 + lane];
    ax += a0.x + a1.x + a2.x + a3.x;
    ay += a0.y + a1.y + a2.y + a3.y;
    az += a0.z + a1.z + a2.z + a3.z;
    aw += a0.w + a1.w + a2.w + a3.w;
  }
  for (; j < end; ++j) {
    int s0 = srcs[j];
    float4 a0 = g4[(size_t)s0 * 16 + lane];
    ax += a0.x; ay += a0.y; az += a0.z; aw += a0.w;
  }

  float dv = dis[v];
  float4 bb = *(const float4*)&bias[lane * 4];
  float4 o;
  o.x = fmaxf(fmaf(dv, ax, bb.x), 0.f);
  o.y = fmaxf(fmaf(dv, ay, bb.y), 0.f);
  o.z = fmaxf(fmaf(dv, az, bb.z), 0.f);
  o.w = fmaxf(fmaf(dv, aw, bb.w), 0.f);
  ((float4*)outp)[(size_t)v * 16 + lane] = o;
}

// ---------------- final FC: out[row] = A[row,:] @ Wfc + bfc ----------------

__global__ __launch_bounds__(256) void k_fc(const float* __restrict__ A,
                                            const float* __restrict__ Wfc,
                                            const float* __restrict__ bfc,
                                            float* __restrict__ outp, int n) {
  __shared__ float Wl[64 * NCLS];
  __shared__ float bl[8];
  int tid = threadIdx.x;
  for (int i = tid; i < 64 * NCLS; i += 256) Wl[i] = Wfc[i];
  if (tid < NCLS) bl[tid] = bfc[tid];
  __syncthreads();
  int row = blockIdx.x * 256 + tid;
  if (row >= n) return;
  float accv[NCLS];
#pragma unroll
  for (int j = 0; j < NCLS; ++j) accv[j] = bl[j];
  const float4* a4 = (const float4*)&A[(size_t)row * 64];
#pragma unroll
  for (int k4 = 0; k4 < 16; ++k4) {
    float4 a = a4[k4];
    const float av[4] = {a.x, a.y, a.z, a.w};
#pragma unroll
    for (int q = 0; q < 4; ++q)
#pragma unroll
      for (int j = 0; j < NCLS; ++j) accv[j] += av[q] * Wl[(k4 * 4 + q) * NCLS + j];
  }
#pragma unroll
  for (int j = 0; j < NCLS; ++j) outp[(size_t)row * NCLS + j] = accv[j];
}

// ---------------- launch ----------------

extern "C" void kernel_launch(void* const* d_in, const int* in_sizes, int n_in,
                              void* d_out, int out_size, void* d_ws, size_t ws_size,
                              hipStream_t stream) {
  const float* x   = (const float*)d_in[0];
  const int*   ei  = (const int*)d_in[1];
  const float* W1  = (const float*)d_in[2];
  const float* b1  = (const float*)d_in[3];
  const float* W2  = (const float*)d_in[4];
  const float* b2  = (const float*)d_in[5];
  const float* Wfc = (const float*)d_in[6];
  const float* bfc = (const float*)d_in[7];
  float* out = (float*)d_out;

  const int n = in_sizes[0] / NFEAT;   // 100000
  const int E = in_sizes[1] / 2;       // 3200000
  const int* src = ei;
  const int* dst = ei + E;

  char* ws = (char*)d_ws;
  size_t off = 0;
  auto alloc = [&](size_t bytes) -> void* {
    void* p = (void*)(ws + off);
    off += (bytes + 255) & ~(size_t)255;
    return p;
  };
  int*   cnt    = (int*)alloc((size_t)n * 4);        // degree, then reused as cursor
  float* dis    = (float*)alloc((size_t)n * 4);
  int*   rowptr = (int*)alloc(((size_t)n + 1) * 4);
  int*   srcs   = (int*)alloc((size_t)E * 4);        // CSR column (src) array
  float* bufA   = (float*)alloc((size_t)n * HID * 4);
  float* bufB   = (float*)alloc((size_t)n * HID * 4);
  const int nb = (n + 1023) / 1024;                  // 98 for n=100000 (<=128)
  int*   bsum   = (int*)alloc((size_t)nb * 4);
  int*   boff   = (int*)alloc((size_t)nb * 4);

  const int gN = (n + 255) / 256;
  const int gE = (E + 255) / 256;

  // degree + normalization
  k_zero_int<<<gN, 256, 0, stream>>>(cnt, n);
  k_count<<<gE, 256, 0, stream>>>(dst, cnt, E);
  k_dis<<<gN, 256, 0, stream>>>(cnt, dis, n);

  // CSR build (shared by both layers)
  k_scan_block<<<nb, 256, 0, stream>>>(cnt, rowptr, bsum, n);
  k_scan_sums<<<1, 128, 0, stream>>>(bsum, boff, nb, rowptr + n);
  k_scan_add<<<nb, 256, 0, stream>>>(rowptr, boff, n);
  k_zero_int<<<gN, 256, 0, stream>>>(cnt, n);  // reuse as scatter cursor
  k_scatter<<<gE, 256, 0, stream>>>(src, dst, rowptr, cnt, srcs, E);

  // layer 1
  k_gemm_scaled<NFEAT><<<(n + 63) / 64, 256, 0, stream>>>(x, W1, dis, bufA, n);
  k_agg_csr<<<(n + 15) / 16, 256, 0, stream>>>(rowptr, srcs, bufA, dis, b1, bufB, n);

  // layer 2
  k_gemm_scaled<HID><<<(n + 63) / 64, 256, 0, stream>>>(bufB, W2, dis, bufA, n);
  k_agg_csr<<<(n + 15) / 16, 256, 0, stream>>>(rowptr, srcs, bufA, dis, b2, bufB, n);

  // FC head
  k_fc<<<(n + 255) / 256, 256, 0, stream>>>(bufB, Wfc, bfc, out, n);
}